// Round 14
// baseline (323.639 us; speedup 1.0000x reference)
//
#include <hip/hip_runtime.h>

typedef __attribute__((ext_vector_type(8))) short short8;
typedef __attribute__((ext_vector_type(4))) float f32x4;

constexpr float BN_EPS = 1e-5f;
#define NBUCKETS 128   // buckets of 1024 nodes; N <= 131072
#define SLOT 24576     // per-bucket edge slot; mean 16384/bucket @ deg 16, +63 sigma headroom

__device__ __forceinline__ ushort f2bf(float f) {
  uint u = __float_as_uint(f);
  u = (u + 0x7fffu + ((u >> 16) & 1u)) >> 16;
  return (ushort)u;
}
__device__ __forceinline__ float bf2f(ushort h) { return __uint_as_float((uint)h << 16); }
__device__ __forceinline__ float bf2f_lo(uint v) { return __uint_as_float(v << 16); }
__device__ __forceinline__ float bf2f_hi(uint v) { return __uint_as_float(v & 0xffff0000u); }

typedef __attribute__((address_space(1))) const unsigned int* as1_cu32;
typedef __attribute__((address_space(3))) unsigned int* as3_u32;
__device__ __forceinline__ void gload_lds16(const void* g, void* l) {
  __builtin_amdgcn_global_load_lds((as1_cu32)g, (as3_u32)l, 16, 0, 0);
}

// ---------------- mega-prep: binscatter + weight casts + x cast + stats zero ----------------

__global__ __launch_bounds__(256) void k_prep(const int* __restrict__ dst, const int* __restrict__ src, int E,
                                              int* __restrict__ bcur, uint* __restrict__ ebuf,
                                              const float* __restrict__ x, ushort* __restrict__ Xb, int n4,
                                              const float* __restrict__ Wl0, const float* __restrict__ Wr0,
                                              const float* __restrict__ Wl1, const float* __restrict__ Wr1,
                                              const float* __restrict__ Wl2, const float* __restrict__ Wr2,
                                              ushort* __restrict__ W0l, ushort* __restrict__ W0r,
                                              ushort* __restrict__ W1l, ushort* __restrict__ W1r,
                                              ushort* __restrict__ Wc, float* __restrict__ statsAll,
                                              int C, int binGrid, int castGrid) {
  int bb = blockIdx.x;
  if (bb < binGrid) {
    __shared__ int h[NBUCKETS];
    __shared__ int base[NBUCKETS];
    __shared__ int cur[NBUCKETS];
    const int e0 = bb * 8192;
    const int e1 = min(e0 + 8192, E);
    for (int i = threadIdx.x; i < NBUCKETS; i += 256) h[i] = 0;
    __syncthreads();
    for (int e = e0 + threadIdx.x * 4; e < e1; e += 1024) {
      int4 d = *reinterpret_cast<const int4*>(&dst[e]);
      if (e + 3 < e1) {
        atomicAdd(&h[d.x >> 10], 1); atomicAdd(&h[d.y >> 10], 1);
        atomicAdd(&h[d.z >> 10], 1); atomicAdd(&h[d.w >> 10], 1);
      } else {
        for (int j = 0; e + j < e1; ++j) atomicAdd(&h[dst[e + j] >> 10], 1);
      }
    }
    __syncthreads();
    if (threadIdx.x < NBUCKETS) {
      base[threadIdx.x] = threadIdx.x * SLOT + atomicAdd(&bcur[threadIdx.x], h[threadIdx.x]);
      cur[threadIdx.x] = 0;
    }
    __syncthreads();
    for (int e = e0 + threadIdx.x * 4; e < e1; e += 1024) {
      int4 d = *reinterpret_cast<const int4*>(&dst[e]);
      int4 s = *reinterpret_cast<const int4*>(&src[e]);
      int dd[4] = {d.x, d.y, d.z, d.w};
      int ss[4] = {s.x, s.y, s.z, s.w};
      for (int j = 0; j < 4 && e + j < e1; ++j) {
        int b = dd[j] >> 10;
        int pos = base[b] + atomicAdd(&cur[b], 1);
        ebuf[pos] = (uint)(dd[j] & 1023) | ((uint)ss[j] << 10);
      }
    }
    return;
  }
  bb -= binGrid;
  if (bb < 64) {
    const float* s = (bb < 16) ? Wl0 : (bb < 32) ? Wr0 : (bb < 48) ? Wl1 : Wr1;
    ushort* d = (bb < 16) ? W0l : (bb < 32) ? W0r : (bb < 48) ? W1l : W1r;
    int i = (bb & 15) * 256 + threadIdx.x;
    float4 v = reinterpret_cast<const float4*>(s)[i];
    ushort4 o;
    o.x = f2bf(v.x); o.y = f2bf(v.y); o.z = f2bf(v.z); o.w = f2bf(v.w);
    reinterpret_cast<ushort4*>(d)[i] = o;
    return;
  }
  bb -= 64;
  if (bb < 64) {
    int i = bb * 256 + threadIdx.x;  // 16384
    int r = i >> 7, k = i & 127;
    float v = 0.f;
    if (r < C) v = Wl2[r * 128 + k];
    else if (r >= 64 && r < 64 + C) v = Wr2[(r - 64) * 128 + k];
    Wc[i] = f2bf(v);
    return;
  }
  bb -= 64;
  if (bb < castGrid) {
    for (int i = bb * 256 + threadIdx.x; i < n4; i += castGrid * 256) {
      float4 v = reinterpret_cast<const float4*>(x)[i];
      ushort4 o;
      o.x = f2bf(v.x); o.y = f2bf(v.y); o.z = f2bf(v.z); o.w = f2bf(v.w);
      reinterpret_cast<ushort4*>(Xb)[i] = o;
    }
    return;
  }
  for (int i = threadIdx.x; i < 512; i += 256) statsAll[i] = 0.f;
}

// per-bucket: node counts, LDS scan, rp/deg/deg_inv, scatter src into csr
__global__ __launch_bounds__(512) void k_bucket_build(const uint* __restrict__ ebuf, const int* __restrict__ bend,
                                                      int* __restrict__ rp, int* __restrict__ deg,
                                                      float* __restrict__ deg_inv, int* __restrict__ csr, int N) {
  __shared__ int cnt[1024];
  __shared__ int pre[1024];
  __shared__ int tmp[1024];
  const int blk = blockIdx.x, tid = threadIdx.x;
  const int base = blk << 10;
  const int p0 = blk * SLOT, p1 = p0 + bend[blk];
  for (int i = tid; i < 1024; i += 512) cnt[i] = 0;
  __syncthreads();
  for (int p = p0 + tid; p < p1; p += 512) atomicAdd(&cnt[ebuf[p] & 1023u], 1);
  __syncthreads();
  for (int i = tid; i < 1024; i += 512) pre[i] = cnt[i];
  __syncthreads();
  for (int off = 1; off < 1024; off <<= 1) {
    for (int i = tid; i < 1024; i += 512) tmp[i] = (i >= off) ? pre[i - off] : 0;
    __syncthreads();
    for (int i = tid; i < 1024; i += 512) pre[i] += tmp[i];
    __syncthreads();
  }
  for (int i = tid; i < 1024; i += 512) {
    int node = base + i;
    if (node < N) {
      int c = cnt[i];
      rp[node] = p0 + pre[i] - c;
      deg[node] = c;
      deg_inv[node] = 1.0f / (float)max(c, 1);
    }
    tmp[i] = pre[i] - cnt[i];  // scatter cursor
  }
  __syncthreads();
  for (int p = p0 + tid; p < p1; p += 512) {
    uint pr = ebuf[p];
    int pos = p0 + atomicAdd(&tmp[pr & 1023u], 1);
    csr[pos] = (int)(pr >> 10);
  }
}

// ---------------- fused mean-agg + dual MFMA GEMM + BN-partials ----------------
// Block = 64 nodes, 512 threads (8 waves). Gather source must be CLEAN bf16 data
// (post-bn_relu): fusing BN into the gather read regressed 50us/layer (R9/R10).
// csr-index loads are rotated one batch ahead to keep gathers in flight.
// R12 lesson: do NOT deepen the per-wave gather window (spills at >110 VGPR).
// R14: raise TLP instead — (512,8) doubles resident blocks (48 VGPR <= 64 cap,
// 4 x 32KB LDS <= 160KB/CU).

__global__ __launch_bounds__(512, 8) void k_fused(const ushort* __restrict__ X, const ushort* __restrict__ Bsrc,
                                                  const ushort* __restrict__ WA, const ushort* __restrict__ WB,
                                                  const int* __restrict__ rp, const int* __restrict__ deg,
                                                  const float* __restrict__ deg_inv, const int* __restrict__ csr,
                                                  float* __restrict__ partial, ushort* __restrict__ Z, int M) {
  __shared__ ushort sA[64 * 128];
  __shared__ ushort sB[64 * 128];
  const int tid = threadIdx.x;
  const int wave = tid >> 6, lane = tid & 63;
  const int rfrag = lane & 15, kgrp = lane >> 4;
  const int li = rfrag;  // 16B column within a 256B row
  const int row0 = blockIdx.x * 64;

  // B-tile staging (in flight across the whole agg phase)
#pragma unroll
  for (int i = 0; i < 2; ++i) {
    int c = wave * 2 + i;
    int lb = c * 1024 + lane * 16;
    int row = lb >> 8, bin = lb & 255;
    int gr = min(row0 + row, M - 1);
    int sb = bin ^ ((row & 7) << 4);
    gload_lds16((const char*)Bsrc + (size_t)gr * 256 + sb, (char*)sB + c * 1024);
  }

  // agg phase: wave handles 8 nodes (2 groups of 4 via kgrp)
  const uint4* X16 = reinterpret_cast<const uint4*>(X);
#pragma unroll
  for (int g = 0; g < 2; ++g) {
    const int lrow = wave * 8 + g * 4 + kgrp;
    const int node = row0 + lrow;
    float a0 = 0.f, a1 = 0.f, a2 = 0.f, a3 = 0.f, a4 = 0.f, a5 = 0.f, a6 = 0.f, a7 = 0.f;
    if (node < M) {
      const int start = rp[node];
      const int c = deg[node];
      int p = 0;
      if (c >= 8) {
        int idx[8];
#pragma unroll
        for (int u = 0; u < 8; ++u) idx[u] = csr[start + u];
        while (true) {
          uint4 v[8];
#pragma unroll
          for (int u = 0; u < 8; ++u) v[u] = X16[(size_t)idx[u] * 16 + li];
          p += 8;
          const bool more = (p + 7 < c);
          if (more) {
#pragma unroll
            for (int u = 0; u < 8; ++u) idx[u] = csr[start + p + u];  // prefetch next batch
          }
#pragma unroll
          for (int u = 0; u < 8; ++u) {
            a0 += bf2f_lo(v[u].x); a1 += bf2f_hi(v[u].x);
            a2 += bf2f_lo(v[u].y); a3 += bf2f_hi(v[u].y);
            a4 += bf2f_lo(v[u].z); a5 += bf2f_hi(v[u].z);
            a6 += bf2f_lo(v[u].w); a7 += bf2f_hi(v[u].w);
          }
          if (!more) break;
        }
      }
      if (p + 3 < c) {
        int idx[4];
#pragma unroll
        for (int u = 0; u < 4; ++u) idx[u] = csr[start + p + u];
        uint4 v[4];
#pragma unroll
        for (int u = 0; u < 4; ++u) v[u] = X16[(size_t)idx[u] * 16 + li];
#pragma unroll
        for (int u = 0; u < 4; ++u) {
          a0 += bf2f_lo(v[u].x); a1 += bf2f_hi(v[u].x);
          a2 += bf2f_lo(v[u].y); a3 += bf2f_hi(v[u].y);
          a4 += bf2f_lo(v[u].z); a5 += bf2f_hi(v[u].z);
          a6 += bf2f_lo(v[u].w); a7 += bf2f_hi(v[u].w);
        }
        p += 4;
      }
      for (; p < c; ++p) {
        uint4 v = X16[(size_t)csr[start + p] * 16 + li];
        a0 += bf2f_lo(v.x); a1 += bf2f_hi(v.x);
        a2 += bf2f_lo(v.y); a3 += bf2f_hi(v.y);
        a4 += bf2f_lo(v.z); a5 += bf2f_hi(v.z);
        a6 += bf2f_lo(v.w); a7 += bf2f_hi(v.w);
      }
      const float di = deg_inv[node];
      a0 *= di; a1 *= di; a2 *= di; a3 *= di;
      a4 *= di; a5 *= di; a6 *= di; a7 *= di;
    }
    uint4 o;
    o.x = (uint)f2bf(a0) | ((uint)f2bf(a1) << 16);
    o.y = (uint)f2bf(a2) | ((uint)f2bf(a3) << 16);
    o.z = (uint)f2bf(a4) | ((uint)f2bf(a5) << 16);
    o.w = (uint)f2bf(a6) | ((uint)f2bf(a7) << 16);
    *reinterpret_cast<uint4*>((char*)sA + lrow * 256 + ((li * 16) ^ ((lrow & 7) << 4))) = o;
  }

  // weight fragments for this wave's column strip
  short8 wfA[4], wfB[4];
  {
    const ushort* wa = WA + (wave * 16 + rfrag) * 128 + kgrp * 8;
    const ushort* wb = WB + (wave * 16 + rfrag) * 128 + kgrp * 8;
#pragma unroll
    for (int s = 0; s < 4; ++s) {
      wfA[s] = *reinterpret_cast<const short8*>(wa + s * 32);
      wfB[s] = *reinterpret_cast<const short8*>(wb + s * 32);
    }
  }
  __syncthreads();  // A-tile ds_writes visible; B-tile gload_lds drained

  f32x4 acc[4];
#pragma unroll
  for (int i = 0; i < 4; ++i) acc[i] = (f32x4){0.f, 0.f, 0.f, 0.f};

  const int rs = (rfrag & 7) << 4;
#pragma unroll
  for (int strip = 0; strip < 4; ++strip) {
    const int r = strip * 16 + rfrag;
    short8 af[4], bf[4];
#pragma unroll
    for (int s = 0; s < 4; ++s) {
      int off = (kgrp * 16 + s * 64) ^ rs;
      af[s] = *reinterpret_cast<const short8*>((const char*)sA + r * 256 + off);
      bf[s] = *reinterpret_cast<const short8*>((const char*)sB + r * 256 + off);
    }
#pragma unroll
    for (int s = 0; s < 4; ++s)
      acc[strip] = __builtin_amdgcn_mfma_f32_16x16x32_bf16(af[s], wfA[s], acc[strip], 0, 0, 0);
#pragma unroll
    for (int s = 0; s < 4; ++s)
      acc[strip] = __builtin_amdgcn_mfma_f32_16x16x32_bf16(bf[s], wfB[s], acc[strip], 0, 0, 0);
  }

  // BN partials (pre-rounding fp32) -> plain per-block stores (fp32 global atomicAdd
  // is a CAS loop on gfx950 — keep it off the hot path)
  {
    float s1 = 0.f, s2 = 0.f;
#pragma unroll
    for (int strip = 0; strip < 4; ++strip) {
#pragma unroll
      for (int rr = 0; rr < 4; ++rr) {
        int grow = row0 + strip * 16 + kgrp * 4 + rr;
        if (grow < M) {
          float v = acc[strip][rr];
          s1 += v;
          s2 = fmaf(v, v, s2);
        }
      }
    }
    s1 += __shfl_xor(s1, 16); s2 += __shfl_xor(s2, 16);
    s1 += __shfl_xor(s1, 32); s2 += __shfl_xor(s2, 32);
    if (kgrp == 0) {
      partial[(size_t)blockIdx.x * 256 + wave * 16 + rfrag] = s1;
      partial[(size_t)blockIdx.x * 256 + 128 + wave * 16 + rfrag] = s2;
    }
  }
  __syncthreads();  // all sA/sB fragment reads done before repack

  // repack into swizzled sA (reused as Z-tile)
  const int cb = (wave * 16 + rfrag) * 2;
#pragma unroll
  for (int strip = 0; strip < 4; ++strip) {
#pragma unroll
    for (int rr = 0; rr < 4; ++rr) {
      int row = strip * 16 + kgrp * 4 + rr;
      *reinterpret_cast<ushort*>((char*)sA + row * 256 + (cb ^ ((row & 7) << 4))) = f2bf(acc[strip][rr]);
    }
  }
  __syncthreads();

  // contiguous Z store (unswizzle on read)
#pragma unroll
  for (int i = 0; i < 2; ++i) {
    int lb = (wave * 2 + i) * 1024 + lane * 16;
    int row = lb >> 8, bin = lb & 255;
    int gr = row0 + row;
    if (gr < M)
      *reinterpret_cast<uint4*>((char*)Z + (size_t)gr * 256 + bin) =
          *reinterpret_cast<const uint4*>((const char*)sA + row * 256 + (bin ^ ((row & 7) << 4)));
  }
}

// ---------------- BN reduce (partials -> stats; off hot path) ----------------

__global__ __launch_bounds__(256) void k_bn_reduce(const float* __restrict__ partial, int nblk,
                                                   float* __restrict__ stats) {
  float acc = 0.f;
  for (int b = blockIdx.x; b < nblk; b += gridDim.x) acc += partial[(size_t)b * 256 + threadIdx.x];
  atomicAdd(&stats[threadIdx.x], acc);
}

// ---------------- standalone BN+ReLU (fused finalize) — launders the gather source ----------------

__global__ __launch_bounds__(256) void k_bn_relu(uint2* __restrict__ Z, int n2, const float* __restrict__ sums,
                                                 const float* __restrict__ g, const float* __restrict__ b,
                                                 float invM) {
  __shared__ float ss[256];
  if (threadIdx.x < 128) {
    int f = threadIdx.x;
    float mean = sums[f] * invM;
    float var = fmaxf(sums[128 + f] * invM - mean * mean, 0.f);
    float sc = g[f] * rsqrtf(var + BN_EPS);
    ss[f] = sc;
    ss[128 + f] = fmaf(-mean, sc, b[f]);
  }
  __syncthreads();
  for (int i = blockIdx.x * 256 + threadIdx.x; i < n2; i += gridDim.x * 256) {
    uint2 v = Z[i];
    int f0 = (i & 31) * 4;
    float a0 = fmaxf(fmaf(bf2f_lo(v.x), ss[f0 + 0], ss[128 + f0 + 0]), 0.f);
    float a1 = fmaxf(fmaf(bf2f_hi(v.x), ss[f0 + 1], ss[128 + f0 + 1]), 0.f);
    float a2 = fmaxf(fmaf(bf2f_lo(v.y), ss[f0 + 2], ss[128 + f0 + 2]), 0.f);
    float a3 = fmaxf(fmaf(bf2f_hi(v.y), ss[f0 + 3], ss[128 + f0 + 3]), 0.f);
    v.x = (uint)f2bf(a0) | ((uint)f2bf(a1) << 16);
    v.y = (uint)f2bf(a2) | ((uint)f2bf(a3) << 16);
    Z[i] = v;
  }
}

// ---------------- layer-2: Yb/Rb = relu(bn(H_raw)) @ Wc^T split ----------------
// BN-on-read is safe here: H is read LINEARLY via global_load_lds (no cross-XCD
// random gather), transform happens in LDS.

__global__ __launch_bounds__(512, 6) void k_gemm1(const ushort* __restrict__ H, const ushort* __restrict__ Wc,
                                                  const float* __restrict__ sums, const float* __restrict__ gw,
                                                  const float* __restrict__ bw, float invM,
                                                  ushort* __restrict__ Yb, ushort* __restrict__ Rb, int M) {
  __shared__ ushort sA[64 * 128];
  __shared__ float ssc[128];
  __shared__ float ssh[128];
  const int tid = threadIdx.x;
  const int wave = tid >> 6, lane = tid & 63;
  const int rfrag = lane & 15, kgrp = lane >> 4;
  const int row0 = blockIdx.x * 64;

  if (tid < 128) {
    float mean = sums[tid] * invM;
    float var = fmaxf(sums[128 + tid] * invM - mean * mean, 0.f);
    float sc = gw[tid] * rsqrtf(var + BN_EPS);
    ssc[tid] = sc;
    ssh[tid] = fmaf(-mean, sc, bw[tid]);
  }

#pragma unroll
  for (int i = 0; i < 2; ++i) {
    int c = wave * 2 + i;
    int lb = c * 1024 + lane * 16;
    int row = lb >> 8, bin = lb & 255;
    int gr = min(row0 + row, M - 1);
    int sb = bin ^ ((row & 7) << 4);
    gload_lds16((const char*)H + (size_t)gr * 256 + sb, (char*)sA + c * 1024);
  }

  short8 wf[4];
  {
    const ushort* wp = Wc + (wave * 16 + rfrag) * 128 + kgrp * 8;
#pragma unroll
    for (int s = 0; s < 4; ++s) wf[s] = *reinterpret_cast<const short8*>(wp + s * 32);
  }
  __syncthreads();

  // BN+ReLU the staged tile in place
#pragma unroll
  for (int i = 0; i < 2; ++i) {
    int addr = (wave * 2 + i) * 1024 + lane * 16;
    int row = addr >> 8, bin = addr & 255;
    int col0 = (bin ^ ((row & 7) << 4)) >> 1;
    uint4 v = *reinterpret_cast<const uint4*>((const char*)sA + addr);
    uint vv[4] = {v.x, v.y, v.z, v.w};
    uint ov[4];
#pragma unroll
    for (int q = 0; q < 4; ++q) {
      int f = col0 + q * 2;
      float xl = fmaxf(fmaf(bf2f_lo(vv[q]), ssc[f], ssh[f]), 0.f);
      float xh = fmaxf(fmaf(bf2f_hi(vv[q]), ssc[f + 1], ssh[f + 1]), 0.f);
      ov[q] = (uint)f2bf(xl) | ((uint)f2bf(xh) << 16);
    }
    *reinterpret_cast<uint4*>((char*)sA + addr) = make_uint4(ov[0], ov[1], ov[2], ov[3]);
  }
  __syncthreads();

  f32x4 acc[4];
#pragma unroll
  for (int i = 0; i < 4; ++i) acc[i] = (f32x4){0.f, 0.f, 0.f, 0.f};
  const int rs = (rfrag & 7) << 4;
#pragma unroll
  for (int strip = 0; strip < 4; ++strip) {
    const int r = strip * 16 + rfrag;
    short8 af[4];
#pragma unroll
    for (int s = 0; s < 4; ++s)
      af[s] = *reinterpret_cast<const short8*>((const char*)sA + r * 256 + ((kgrp * 16 + s * 64) ^ rs));
#pragma unroll
    for (int s = 0; s < 4; ++s)
      acc[strip] = __builtin_amdgcn_mfma_f32_16x16x32_bf16(af[s], wf[s], acc[strip], 0, 0, 0);
  }
  __syncthreads();

  const int cb = (wave * 16 + rfrag) * 2;
#pragma unroll
  for (int strip = 0; strip < 4; ++strip) {
#pragma unroll
    for (int rr = 0; rr < 4; ++rr) {
      int row = strip * 16 + kgrp * 4 + rr;
      *reinterpret_cast<ushort*>((char*)sA + row * 256 + (cb ^ ((row & 7) << 4))) = f2bf(acc[strip][rr]);
    }
  }
  __syncthreads();

#pragma unroll
  for (int i = 0; i < 2; ++i) {
    int lb = (wave * 2 + i) * 1024 + lane * 16;
    int row = lb >> 8, bin = lb & 255;
    int gr = row0 + row;
    if (gr < M) {
      uint4 v = *reinterpret_cast<const uint4*>((const char*)sA + row * 256 + (bin ^ ((row & 7) << 4)));
      if (bin < 128) *reinterpret_cast<uint4*>((char*)Yb + (size_t)gr * 128 + bin) = v;
      else *reinterpret_cast<uint4*>((char*)Rb + (size_t)gr * 128 + (bin - 128)) = v;
    }
  }
}

// ---------------- layer-2 aggregation: out = mean(Y) + R + bias (fp32 out) ----------------

__global__ __launch_bounds__(256) void k_agg47(const ushort* __restrict__ Yb, const ushort* __restrict__ Rb,
                                               const float* __restrict__ bias, const int* __restrict__ rp,
                                               const int* __restrict__ deg, const float* __restrict__ deg_inv,
                                               const int* __restrict__ csr, float* __restrict__ out,
                                               int N, int C) {
  const int wave = threadIdx.x >> 6, lane = threadIdx.x & 63;
  const int sub = lane >> 3, li = lane & 7;
  const int node = blockIdx.x * 32 + wave * 8 + sub;
  if (node >= N) return;
  const int start = rp[node];
  const int c = deg[node];
  const uint4* Y16 = reinterpret_cast<const uint4*>(Yb);
  float a0 = 0.f, a1 = 0.f, a2 = 0.f, a3 = 0.f, a4 = 0.f, a5 = 0.f, a6 = 0.f, a7 = 0.f;
  int p = 0;
  for (; p + 7 < c; p += 8) {
    int idx[8];
#pragma unroll
    for (int u = 0; u < 8; ++u) idx[u] = csr[start + p + u];
    uint4 v[8];
#pragma unroll
    for (int u = 0; u < 8; ++u) v[u] = Y16[(size_t)idx[u] * 8 + li];
#pragma unroll
    for (int u = 0; u < 8; ++u) {
      a0 += bf2f_lo(v[u].x); a1 += bf2f_hi(v[u].x);
      a2 += bf2f_lo(v[u].y); a3 += bf2f_hi(v[u].y);
      a4 += bf2f_lo(v[u].z); a5 += bf2f_hi(v[u].z);
      a6 += bf2f_lo(v[u].w); a7 += bf2f_hi(v[u].w);
    }
  }
  for (; p < c; ++p) {
    uint4 v = Y16[(size_t)csr[start + p] * 8 + li];
    a0 += bf2f_lo(v.x); a1 += bf2f_hi(v.x);
    a2 += bf2f_lo(v.y); a3 += bf2f_hi(v.y);
    a4 += bf2f_lo(v.z); a5 += bf2f_hi(v.z);
    a6 += bf2f_lo(v.w); a7 += bf2f_hi(v.w);
  }
  const float di = deg_inv[node];
  uint4 sv = reinterpret_cast<const uint4*>(Rb)[(size_t)node * 8 + li];
  float s[8] = {bf2f_lo(sv.x), bf2f_hi(sv.x), bf2f_lo(sv.y), bf2f_hi(sv.y),
                bf2f_lo(sv.z), bf2f_hi(sv.z), bf2f_lo(sv.w), bf2f_hi(sv.w)};
  float a[8] = {a0, a1, a2, a3, a4, a5, a6, a7};
#pragma unroll
  for (int j = 0; j < 8; ++j) {
    int f = li * 8 + j;
    if (f < C) out[(size_t)node * C + f] = fmaf(a[j], di, s[j] + bias[f]);
  }
}

// ---------------- host launch ----------------

extern "C" void kernel_launch(void* const* d_in, const int* in_sizes, int n_in,
                              void* d_out, int out_size, void* d_ws, size_t ws_size,
                              hipStream_t stream) {
  const float* x   = (const float*)d_in[0];
  const int*   ei  = (const int*)d_in[1];
  const float* Wl0 = (const float*)d_in[2];
  const float* Wr0 = (const float*)d_in[4];
  const float* g0  = (const float*)d_in[5];
  const float* b0  = (const float*)d_in[6];
  const float* Wl1 = (const float*)d_in[7];
  const float* Wr1 = (const float*)d_in[9];
  const float* g1  = (const float*)d_in[10];
  const float* b1  = (const float*)d_in[11];
  const float* Wl2 = (const float*)d_in[12];
  const float* bl2 = (const float*)d_in[13];
  const float* Wr2 = (const float*)d_in[14];

  const int N = in_sizes[0] / 128;
  const int E = in_sizes[1] / 2;
  const int C = in_sizes[13];  // 47

  const int* edst = ei;
  const int* esrc = ei + E;

  char* w = (char*)d_ws;
  auto al = [](size_t v) { return (v + 255) & ~(size_t)255; };
  size_t off = 0;
  int*    bcur    = (int*)(w + off);    off = al(off + NBUCKETS * 4);
  float*  stats   = (float*)(w + off);  off = al(off + 512 * 4);   // stats0[256] + stats1[256]
  int*    rp      = (int*)(w + off);    off = al(off + (size_t)N * 4);
  int*    deg     = (int*)(w + off);    off = al(off + (size_t)N * 4);
  float*  deg_inv = (float*)(w + off);  off = al(off + (size_t)N * 4);
  int*    csr     = (int*)(w + off);    off = al(off + (size_t)NBUCKETS * SLOT * 4);
  uint*   ebuf    = (uint*)(w + off);   off = al(off + (size_t)NBUCKETS * SLOT * 4);
  ushort* Xb      = (ushort*)(w + off); off = al(off + (size_t)N * 128 * 2);
  ushort* hA      = (ushort*)(w + off); off = al(off + (size_t)N * 128 * 2);
  ushort* hB      = (ushort*)(w + off); off = al(off + (size_t)N * 128 * 2);
  ushort* W0l     = (ushort*)(w + off); off = al(off + 16384 * 2);
  ushort* W0r     = (ushort*)(w + off); off = al(off + 16384 * 2);
  ushort* W1l     = (ushort*)(w + off); off = al(off + 16384 * 2);
  ushort* W1r     = (ushort*)(w + off); off = al(off + 16384 * 2);
  ushort* Wc      = (ushort*)(w + off); off = al(off + 16384 * 2);
  const int nblkG = (N + 63) / 64;
  float*  partial = (float*)(w + off);  off = al(off + (size_t)nblkG * 256 * 4);

  float* stats0 = stats;
  float* stats1 = stats + 256;
  ushort* Yb = hB;                    // layer-2 output reuses hB
  ushort* Rb = hB + (size_t)N * 64;

  const int binGrid = (E + 8191) / 8192;
  const int castGrid = 384;
  const int nbBuck = (N + 1023) / 1024;
  const int agg47Grid = (N + 31) / 32;
  const float invM = 1.0f / (float)N;

  hipMemsetAsync(bcur, 0, NBUCKETS * 4, stream);

  // mega-prep: binscatter + weight casts + x cast + stats zero
  k_prep<<<binGrid + 128 + castGrid + 1, 256, 0, stream>>>(
      edst, esrc, E, bcur, ebuf, x, Xb, N * 32,
      Wl0, Wr0, Wl1, Wr1, Wl2, Wr2, W0l, W0r, W1l, W1r, Wc, stats, C, binGrid, castGrid);

  k_bucket_build<<<nbBuck, 512, 0, stream>>>(ebuf, bcur, rp, deg, deg_inv, csr, N);

  // Layer 0: raw inputs -> hB = Z0; partials -> stats0
  k_fused<<<nblkG, 512, 0, stream>>>(Xb, Xb, W0l, W0r, rp, deg, deg_inv, csr, partial, hB, N);
  k_bn_reduce<<<64, 256, 0, stream>>>(partial, nblkG, stats0);

  // BN+ReLU hB in place (launders the gather source for layer 1)
  k_bn_relu<<<2048, 256, 0, stream>>>((uint2*)hB, N * 32, stats0, g0, b0, invM);

  // Layer 1: clean hB -> hA = Z1; partials -> stats1
  k_fused<<<nblkG, 512, 0, stream>>>(hB, hB, W1l, W1r, rp, deg, deg_inv, csr, partial, hA, N);
  k_bn_reduce<<<64, 256, 0, stream>>>(partial, nblkG, stats1);

  // Layer 2: transform relu(bn(Z1)) @ Wc^T (BN on linear read; split Yb/Rb), then aggregate
  k_gemm1<<<nblkG, 512, 0, stream>>>(hA, Wc, stats1, g1, b1, invM, Yb, Rb, N);
  k_agg47<<<agg47Grid, 256, 0, stream>>>(Yb, Rb, bl2, rp, deg, deg_inv, csr, (float*)d_out, N, C);
}

// Round 15
// 294.645 us; speedup vs baseline: 1.0984x; 1.0984x over previous
//
#include <hip/hip_runtime.h>

typedef __attribute__((ext_vector_type(8))) short short8;
typedef __attribute__((ext_vector_type(4))) float f32x4;

constexpr float BN_EPS = 1e-5f;
#define NBUCKETS 128   // buckets of 1024 nodes; N <= 131072
#define SLOT 24576     // per-bucket edge slot; mean 16384/bucket @ deg 16, +63 sigma headroom

__device__ __forceinline__ ushort f2bf(float f) {
  uint u = __float_as_uint(f);
  u = (u + 0x7fffu + ((u >> 16) & 1u)) >> 16;
  return (ushort)u;
}
__device__ __forceinline__ float bf2f(ushort h) { return __uint_as_float((uint)h << 16); }
__device__ __forceinline__ float bf2f_lo(uint v) { return __uint_as_float(v << 16); }
__device__ __forceinline__ float bf2f_hi(uint v) { return __uint_as_float(v & 0xffff0000u); }

typedef __attribute__((address_space(1))) const unsigned int* as1_cu32;
typedef __attribute__((address_space(3))) unsigned int* as3_u32;
__device__ __forceinline__ void gload_lds16(const void* g, void* l) {
  __builtin_amdgcn_global_load_lds((as1_cu32)g, (as3_u32)l, 16, 0, 0);
}

// ---------------- mega-prep: binscatter + weight casts + x cast + stats zero ----------------

__global__ __launch_bounds__(256) void k_prep(const int* __restrict__ dst, const int* __restrict__ src, int E,
                                              int* __restrict__ bcur, uint* __restrict__ ebuf,
                                              const float* __restrict__ x, ushort* __restrict__ Xb, int n4,
                                              const float* __restrict__ Wl0, const float* __restrict__ Wr0,
                                              const float* __restrict__ Wl1, const float* __restrict__ Wr1,
                                              const float* __restrict__ Wl2, const float* __restrict__ Wr2,
                                              ushort* __restrict__ W0l, ushort* __restrict__ W0r,
                                              ushort* __restrict__ W1l, ushort* __restrict__ W1r,
                                              ushort* __restrict__ Wc, float* __restrict__ statsAll,
                                              int C, int binGrid, int castGrid) {
  int bb = blockIdx.x;
  if (bb < binGrid) {
    __shared__ int h[NBUCKETS];
    __shared__ int base[NBUCKETS];
    __shared__ int cur[NBUCKETS];
    const int e0 = bb * 8192;
    const int e1 = min(e0 + 8192, E);
    for (int i = threadIdx.x; i < NBUCKETS; i += 256) h[i] = 0;
    __syncthreads();
    for (int e = e0 + threadIdx.x * 4; e < e1; e += 1024) {
      int4 d = *reinterpret_cast<const int4*>(&dst[e]);
      if (e + 3 < e1) {
        atomicAdd(&h[d.x >> 10], 1); atomicAdd(&h[d.y >> 10], 1);
        atomicAdd(&h[d.z >> 10], 1); atomicAdd(&h[d.w >> 10], 1);
      } else {
        for (int j = 0; e + j < e1; ++j) atomicAdd(&h[dst[e + j] >> 10], 1);
      }
    }
    __syncthreads();
    if (threadIdx.x < NBUCKETS) {
      base[threadIdx.x] = threadIdx.x * SLOT + atomicAdd(&bcur[threadIdx.x], h[threadIdx.x]);
      cur[threadIdx.x] = 0;
    }
    __syncthreads();
    for (int e = e0 + threadIdx.x * 4; e < e1; e += 1024) {
      int4 d = *reinterpret_cast<const int4*>(&dst[e]);
      int4 s = *reinterpret_cast<const int4*>(&src[e]);
      int dd[4] = {d.x, d.y, d.z, d.w};
      int ss[4] = {s.x, s.y, s.z, s.w};
      for (int j = 0; j < 4 && e + j < e1; ++j) {
        int b = dd[j] >> 10;
        int pos = base[b] + atomicAdd(&cur[b], 1);
        ebuf[pos] = (uint)(dd[j] & 1023) | ((uint)ss[j] << 10);
      }
    }
    return;
  }
  bb -= binGrid;
  if (bb < 64) {
    const float* s = (bb < 16) ? Wl0 : (bb < 32) ? Wr0 : (bb < 48) ? Wl1 : Wr1;
    ushort* d = (bb < 16) ? W0l : (bb < 32) ? W0r : (bb < 48) ? W1l : W1r;
    int i = (bb & 15) * 256 + threadIdx.x;
    float4 v = reinterpret_cast<const float4*>(s)[i];
    ushort4 o;
    o.x = f2bf(v.x); o.y = f2bf(v.y); o.z = f2bf(v.z); o.w = f2bf(v.w);
    reinterpret_cast<ushort4*>(d)[i] = o;
    return;
  }
  bb -= 64;
  if (bb < 64) {
    int i = bb * 256 + threadIdx.x;  // 16384
    int r = i >> 7, k = i & 127;
    float v = 0.f;
    if (r < C) v = Wl2[r * 128 + k];
    else if (r >= 64 && r < 64 + C) v = Wr2[(r - 64) * 128 + k];
    Wc[i] = f2bf(v);
    return;
  }
  bb -= 64;
  if (bb < castGrid) {
    for (int i = bb * 256 + threadIdx.x; i < n4; i += castGrid * 256) {
      float4 v = reinterpret_cast<const float4*>(x)[i];
      ushort4 o;
      o.x = f2bf(v.x); o.y = f2bf(v.y); o.z = f2bf(v.z); o.w = f2bf(v.w);
      reinterpret_cast<ushort4*>(Xb)[i] = o;
    }
    return;
  }
  for (int i = threadIdx.x; i < 512; i += 256) statsAll[i] = 0.f;
}

// per-bucket: node counts, LDS scan, rp/deg/deg_inv, scatter src into csr
__global__ __launch_bounds__(512) void k_bucket_build(const uint* __restrict__ ebuf, const int* __restrict__ bend,
                                                      int* __restrict__ rp, int* __restrict__ deg,
                                                      float* __restrict__ deg_inv, int* __restrict__ csr, int N) {
  __shared__ int cnt[1024];
  __shared__ int pre[1024];
  __shared__ int tmp[1024];
  const int blk = blockIdx.x, tid = threadIdx.x;
  const int base = blk << 10;
  const int p0 = blk * SLOT, p1 = p0 + bend[blk];
  for (int i = tid; i < 1024; i += 512) cnt[i] = 0;
  __syncthreads();
  for (int p = p0 + tid; p < p1; p += 512) atomicAdd(&cnt[ebuf[p] & 1023u], 1);
  __syncthreads();
  for (int i = tid; i < 1024; i += 512) pre[i] = cnt[i];
  __syncthreads();
  for (int off = 1; off < 1024; off <<= 1) {
    for (int i = tid; i < 1024; i += 512) tmp[i] = (i >= off) ? pre[i - off] : 0;
    __syncthreads();
    for (int i = tid; i < 1024; i += 512) pre[i] += tmp[i];
    __syncthreads();
  }
  for (int i = tid; i < 1024; i += 512) {
    int node = base + i;
    if (node < N) {
      int c = cnt[i];
      rp[node] = p0 + pre[i] - c;
      deg[node] = c;
      deg_inv[node] = 1.0f / (float)max(c, 1);
    }
    tmp[i] = pre[i] - cnt[i];  // scatter cursor
  }
  __syncthreads();
  for (int p = p0 + tid; p < p1; p += 512) {
    uint pr = ebuf[p];
    int pos = p0 + atomicAdd(&tmp[pr & 1023u], 1);
    csr[pos] = (int)(pr >> 10);
  }
}

// ---------------- fused mean-agg + dual MFMA GEMM + BN-partials ----------------
// Block = 64 nodes, 512 threads (8 waves). Gather source must be CLEAN bf16 data
// (post-bn_relu): fusing BN into the gather read regressed 50us/layer (R9/R10).
// csr-index loads are rotated one batch ahead to keep gathers in flight.
// R12: 16-deep interleave spills (>110 VGPR). R14: (512,8) caps VGPR at 64 ->
// compiler spills to 32 VGPR (92MB scratch writes). (512,6) caps at ~85 >= 48:
// 3 blocks/CU without spilling — the last untested occupancy point.

__global__ __launch_bounds__(512, 6) void k_fused(const ushort* __restrict__ X, const ushort* __restrict__ Bsrc,
                                                  const ushort* __restrict__ WA, const ushort* __restrict__ WB,
                                                  const int* __restrict__ rp, const int* __restrict__ deg,
                                                  const float* __restrict__ deg_inv, const int* __restrict__ csr,
                                                  float* __restrict__ partial, ushort* __restrict__ Z, int M) {
  __shared__ ushort sA[64 * 128];
  __shared__ ushort sB[64 * 128];
  const int tid = threadIdx.x;
  const int wave = tid >> 6, lane = tid & 63;
  const int rfrag = lane & 15, kgrp = lane >> 4;
  const int li = rfrag;  // 16B column within a 256B row
  const int row0 = blockIdx.x * 64;

  // B-tile staging (in flight across the whole agg phase)
#pragma unroll
  for (int i = 0; i < 2; ++i) {
    int c = wave * 2 + i;
    int lb = c * 1024 + lane * 16;
    int row = lb >> 8, bin = lb & 255;
    int gr = min(row0 + row, M - 1);
    int sb = bin ^ ((row & 7) << 4);
    gload_lds16((const char*)Bsrc + (size_t)gr * 256 + sb, (char*)sB + c * 1024);
  }

  // agg phase: wave handles 8 nodes (2 groups of 4 via kgrp)
  const uint4* X16 = reinterpret_cast<const uint4*>(X);
#pragma unroll
  for (int g = 0; g < 2; ++g) {
    const int lrow = wave * 8 + g * 4 + kgrp;
    const int node = row0 + lrow;
    float a0 = 0.f, a1 = 0.f, a2 = 0.f, a3 = 0.f, a4 = 0.f, a5 = 0.f, a6 = 0.f, a7 = 0.f;
    if (node < M) {
      const int start = rp[node];
      const int c = deg[node];
      int p = 0;
      if (c >= 8) {
        int idx[8];
#pragma unroll
        for (int u = 0; u < 8; ++u) idx[u] = csr[start + u];
        while (true) {
          uint4 v[8];
#pragma unroll
          for (int u = 0; u < 8; ++u) v[u] = X16[(size_t)idx[u] * 16 + li];
          p += 8;
          const bool more = (p + 7 < c);
          if (more) {
#pragma unroll
            for (int u = 0; u < 8; ++u) idx[u] = csr[start + p + u];  // prefetch next batch
          }
#pragma unroll
          for (int u = 0; u < 8; ++u) {
            a0 += bf2f_lo(v[u].x); a1 += bf2f_hi(v[u].x);
            a2 += bf2f_lo(v[u].y); a3 += bf2f_hi(v[u].y);
            a4 += bf2f_lo(v[u].z); a5 += bf2f_hi(v[u].z);
            a6 += bf2f_lo(v[u].w); a7 += bf2f_hi(v[u].w);
          }
          if (!more) break;
        }
      }
      if (p + 3 < c) {
        int idx[4];
#pragma unroll
        for (int u = 0; u < 4; ++u) idx[u] = csr[start + p + u];
        uint4 v[4];
#pragma unroll
        for (int u = 0; u < 4; ++u) v[u] = X16[(size_t)idx[u] * 16 + li];
#pragma unroll
        for (int u = 0; u < 4; ++u) {
          a0 += bf2f_lo(v[u].x); a1 += bf2f_hi(v[u].x);
          a2 += bf2f_lo(v[u].y); a3 += bf2f_hi(v[u].y);
          a4 += bf2f_lo(v[u].z); a5 += bf2f_hi(v[u].z);
          a6 += bf2f_lo(v[u].w); a7 += bf2f_hi(v[u].w);
        }
        p += 4;
      }
      for (; p < c; ++p) {
        uint4 v = X16[(size_t)csr[start + p] * 16 + li];
        a0 += bf2f_lo(v.x); a1 += bf2f_hi(v.x);
        a2 += bf2f_lo(v.y); a3 += bf2f_hi(v.y);
        a4 += bf2f_lo(v.z); a5 += bf2f_hi(v.z);
        a6 += bf2f_lo(v.w); a7 += bf2f_hi(v.w);
      }
      const float di = deg_inv[node];
      a0 *= di; a1 *= di; a2 *= di; a3 *= di;
      a4 *= di; a5 *= di; a6 *= di; a7 *= di;
    }
    uint4 o;
    o.x = (uint)f2bf(a0) | ((uint)f2bf(a1) << 16);
    o.y = (uint)f2bf(a2) | ((uint)f2bf(a3) << 16);
    o.z = (uint)f2bf(a4) | ((uint)f2bf(a5) << 16);
    o.w = (uint)f2bf(a6) | ((uint)f2bf(a7) << 16);
    *reinterpret_cast<uint4*>((char*)sA + lrow * 256 + ((li * 16) ^ ((lrow & 7) << 4))) = o;
  }

  // weight fragments for this wave's column strip
  short8 wfA[4], wfB[4];
  {
    const ushort* wa = WA + (wave * 16 + rfrag) * 128 + kgrp * 8;
    const ushort* wb = WB + (wave * 16 + rfrag) * 128 + kgrp * 8;
#pragma unroll
    for (int s = 0; s < 4; ++s) {
      wfA[s] = *reinterpret_cast<const short8*>(wa + s * 32);
      wfB[s] = *reinterpret_cast<const short8*>(wb + s * 32);
    }
  }
  __syncthreads();  // A-tile ds_writes visible; B-tile gload_lds drained

  f32x4 acc[4];
#pragma unroll
  for (int i = 0; i < 4; ++i) acc[i] = (f32x4){0.f, 0.f, 0.f, 0.f};

  const int rs = (rfrag & 7) << 4;
#pragma unroll
  for (int strip = 0; strip < 4; ++strip) {
    const int r = strip * 16 + rfrag;
    short8 af[4], bf[4];
#pragma unroll
    for (int s = 0; s < 4; ++s) {
      int off = (kgrp * 16 + s * 64) ^ rs;
      af[s] = *reinterpret_cast<const short8*>((const char*)sA + r * 256 + off);
      bf[s] = *reinterpret_cast<const short8*>((const char*)sB + r * 256 + off);
    }
#pragma unroll
    for (int s = 0; s < 4; ++s)
      acc[strip] = __builtin_amdgcn_mfma_f32_16x16x32_bf16(af[s], wfA[s], acc[strip], 0, 0, 0);
#pragma unroll
    for (int s = 0; s < 4; ++s)
      acc[strip] = __builtin_amdgcn_mfma_f32_16x16x32_bf16(bf[s], wfB[s], acc[strip], 0, 0, 0);
  }

  // BN partials (pre-rounding fp32) -> plain per-block stores (fp32 global atomicAdd
  // is a CAS loop on gfx950 — keep it off the hot path)
  {
    float s1 = 0.f, s2 = 0.f;
#pragma unroll
    for (int strip = 0; strip < 4; ++strip) {
#pragma unroll
      for (int rr = 0; rr < 4; ++rr) {
        int grow = row0 + strip * 16 + kgrp * 4 + rr;
        if (grow < M) {
          float v = acc[strip][rr];
          s1 += v;
          s2 = fmaf(v, v, s2);
        }
      }
    }
    s1 += __shfl_xor(s1, 16); s2 += __shfl_xor(s2, 16);
    s1 += __shfl_xor(s1, 32); s2 += __shfl_xor(s2, 32);
    if (kgrp == 0) {
      partial[(size_t)blockIdx.x * 256 + wave * 16 + rfrag] = s1;
      partial[(size_t)blockIdx.x * 256 + 128 + wave * 16 + rfrag] = s2;
    }
  }
  __syncthreads();  // all sA/sB fragment reads done before repack

  // repack into swizzled sA (reused as Z-tile)
  const int cb = (wave * 16 + rfrag) * 2;
#pragma unroll
  for (int strip = 0; strip < 4; ++strip) {
#pragma unroll
    for (int rr = 0; rr < 4; ++rr) {
      int row = strip * 16 + kgrp * 4 + rr;
      *reinterpret_cast<ushort*>((char*)sA + row * 256 + (cb ^ ((row & 7) << 4))) = f2bf(acc[strip][rr]);
    }
  }
  __syncthreads();

  // contiguous Z store (unswizzle on read)
#pragma unroll
  for (int i = 0; i < 2; ++i) {
    int lb = (wave * 2 + i) * 1024 + lane * 16;
    int row = lb >> 8, bin = lb & 255;
    int gr = row0 + row;
    if (gr < M)
      *reinterpret_cast<uint4*>((char*)Z + (size_t)gr * 256 + bin) =
          *reinterpret_cast<const uint4*>((const char*)sA + row * 256 + (bin ^ ((row & 7) << 4)));
  }
}

// ---------------- BN reduce (partials -> stats; off hot path) ----------------

__global__ __launch_bounds__(256) void k_bn_reduce(const float* __restrict__ partial, int nblk,
                                                   float* __restrict__ stats) {
  float acc = 0.f;
  for (int b = blockIdx.x; b < nblk; b += gridDim.x) acc += partial[(size_t)b * 256 + threadIdx.x];
  atomicAdd(&stats[threadIdx.x], acc);
}

// ---------------- standalone BN+ReLU (fused finalize) — launders the gather source ----------------

__global__ __launch_bounds__(256) void k_bn_relu(uint2* __restrict__ Z, int n2, const float* __restrict__ sums,
                                                 const float* __restrict__ g, const float* __restrict__ b,
                                                 float invM) {
  __shared__ float ss[256];
  if (threadIdx.x < 128) {
    int f = threadIdx.x;
    float mean = sums[f] * invM;
    float var = fmaxf(sums[128 + f] * invM - mean * mean, 0.f);
    float sc = g[f] * rsqrtf(var + BN_EPS);
    ss[f] = sc;
    ss[128 + f] = fmaf(-mean, sc, b[f]);
  }
  __syncthreads();
  for (int i = blockIdx.x * 256 + threadIdx.x; i < n2; i += gridDim.x * 256) {
    uint2 v = Z[i];
    int f0 = (i & 31) * 4;
    float a0 = fmaxf(fmaf(bf2f_lo(v.x), ss[f0 + 0], ss[128 + f0 + 0]), 0.f);
    float a1 = fmaxf(fmaf(bf2f_hi(v.x), ss[f0 + 1], ss[128 + f0 + 1]), 0.f);
    float a2 = fmaxf(fmaf(bf2f_lo(v.y), ss[f0 + 2], ss[128 + f0 + 2]), 0.f);
    float a3 = fmaxf(fmaf(bf2f_hi(v.y), ss[f0 + 3], ss[128 + f0 + 3]), 0.f);
    v.x = (uint)f2bf(a0) | ((uint)f2bf(a1) << 16);
    v.y = (uint)f2bf(a2) | ((uint)f2bf(a3) << 16);
    Z[i] = v;
  }
}

// ---------------- layer-2: Yb/Rb = relu(bn(H_raw)) @ Wc^T split ----------------
// BN-on-read is safe here: H is read LINEARLY via global_load_lds (no cross-XCD
// random gather), transform happens in LDS.

__global__ __launch_bounds__(512, 6) void k_gemm1(const ushort* __restrict__ H, const ushort* __restrict__ Wc,
                                                  const float* __restrict__ sums, const float* __restrict__ gw,
                                                  const float* __restrict__ bw, float invM,
                                                  ushort* __restrict__ Yb, ushort* __restrict__ Rb, int M) {
  __shared__ ushort sA[64 * 128];
  __shared__ float ssc[128];
  __shared__ float ssh[128];
  const int tid = threadIdx.x;
  const int wave = tid >> 6, lane = tid & 63;
  const int rfrag = lane & 15, kgrp = lane >> 4;
  const int row0 = blockIdx.x * 64;

  if (tid < 128) {
    float mean = sums[tid] * invM;
    float var = fmaxf(sums[128 + tid] * invM - mean * mean, 0.f);
    float sc = gw[tid] * rsqrtf(var + BN_EPS);
    ssc[tid] = sc;
    ssh[tid] = fmaf(-mean, sc, bw[tid]);
  }

#pragma unroll
  for (int i = 0; i < 2; ++i) {
    int c = wave * 2 + i;
    int lb = c * 1024 + lane * 16;
    int row = lb >> 8, bin = lb & 255;
    int gr = min(row0 + row, M - 1);
    int sb = bin ^ ((row & 7) << 4);
    gload_lds16((const char*)H + (size_t)gr * 256 + sb, (char*)sA + c * 1024);
  }

  short8 wf[4];
  {
    const ushort* wp = Wc + (wave * 16 + rfrag) * 128 + kgrp * 8;
#pragma unroll
    for (int s = 0; s < 4; ++s) wf[s] = *reinterpret_cast<const short8*>(wp + s * 32);
  }
  __syncthreads();

  // BN+ReLU the staged tile in place
#pragma unroll
  for (int i = 0; i < 2; ++i) {
    int addr = (wave * 2 + i) * 1024 + lane * 16;
    int row = addr >> 8, bin = addr & 255;
    int col0 = (bin ^ ((row & 7) << 4)) >> 1;
    uint4 v = *reinterpret_cast<const uint4*>((const char*)sA + addr);
    uint vv[4] = {v.x, v.y, v.z, v.w};
    uint ov[4];
#pragma unroll
    for (int q = 0; q < 4; ++q) {
      int f = col0 + q * 2;
      float xl = fmaxf(fmaf(bf2f_lo(vv[q]), ssc[f], ssh[f]), 0.f);
      float xh = fmaxf(fmaf(bf2f_hi(vv[q]), ssc[f + 1], ssh[f + 1]), 0.f);
      ov[q] = (uint)f2bf(xl) | ((uint)f2bf(xh) << 16);
    }
    *reinterpret_cast<uint4*>((char*)sA + addr) = make_uint4(ov[0], ov[1], ov[2], ov[3]);
  }
  __syncthreads();

  f32x4 acc[4];
#pragma unroll
  for (int i = 0; i < 4; ++i) acc[i] = (f32x4){0.f, 0.f, 0.f, 0.f};
  const int rs = (rfrag & 7) << 4;
#pragma unroll
  for (int strip = 0; strip < 4; ++strip) {
    const int r = strip * 16 + rfrag;
    short8 af[4];
#pragma unroll
    for (int s = 0; s < 4; ++s)
      af[s] = *reinterpret_cast<const short8*>((const char*)sA + r * 256 + ((kgrp * 16 + s * 64) ^ rs));
#pragma unroll
    for (int s = 0; s < 4; ++s)
      acc[strip] = __builtin_amdgcn_mfma_f32_16x16x32_bf16(af[s], wf[s], acc[strip], 0, 0, 0);
  }
  __syncthreads();

  const int cb = (wave * 16 + rfrag) * 2;
#pragma unroll
  for (int strip = 0; strip < 4; ++strip) {
#pragma unroll
    for (int rr = 0; rr < 4; ++rr) {
      int row = strip * 16 + kgrp * 4 + rr;
      *reinterpret_cast<ushort*>((char*)sA + row * 256 + (cb ^ ((row & 7) << 4))) = f2bf(acc[strip][rr]);
    }
  }
  __syncthreads();

#pragma unroll
  for (int i = 0; i < 2; ++i) {
    int lb = (wave * 2 + i) * 1024 + lane * 16;
    int row = lb >> 8, bin = lb & 255;
    int gr = row0 + row;
    if (gr < M) {
      uint4 v = *reinterpret_cast<const uint4*>((const char*)sA + row * 256 + (bin ^ ((row & 7) << 4)));
      if (bin < 128) *reinterpret_cast<uint4*>((char*)Yb + (size_t)gr * 128 + bin) = v;
      else *reinterpret_cast<uint4*>((char*)Rb + (size_t)gr * 128 + (bin - 128)) = v;
    }
  }
}

// ---------------- layer-2 aggregation: out = mean(Y) + R + bias (fp32 out) ----------------

__global__ __launch_bounds__(256) void k_agg47(const ushort* __restrict__ Yb, const ushort* __restrict__ Rb,
                                               const float* __restrict__ bias, const int* __restrict__ rp,
                                               const int* __restrict__ deg, const float* __restrict__ deg_inv,
                                               const int* __restrict__ csr, float* __restrict__ out,
                                               int N, int C) {
  const int wave = threadIdx.x >> 6, lane = threadIdx.x & 63;
  const int sub = lane >> 3, li = lane & 7;
  const int node = blockIdx.x * 32 + wave * 8 + sub;
  if (node >= N) return;
  const int start = rp[node];
  const int c = deg[node];
  const uint4* Y16 = reinterpret_cast<const uint4*>(Yb);
  float a0 = 0.f, a1 = 0.f, a2 = 0.f, a3 = 0.f, a4 = 0.f, a5 = 0.f, a6 = 0.f, a7 = 0.f;
  int p = 0;
  for (; p + 7 < c; p += 8) {
    int idx[8];
#pragma unroll
    for (int u = 0; u < 8; ++u) idx[u] = csr[start + p + u];
    uint4 v[8];
#pragma unroll
    for (int u = 0; u < 8; ++u) v[u] = Y16[(size_t)idx[u] * 8 + li];
#pragma unroll
    for (int u = 0; u < 8; ++u) {
      a0 += bf2f_lo(v[u].x); a1 += bf2f_hi(v[u].x);
      a2 += bf2f_lo(v[u].y); a3 += bf2f_hi(v[u].y);
      a4 += bf2f_lo(v[u].z); a5 += bf2f_hi(v[u].z);
      a6 += bf2f_lo(v[u].w); a7 += bf2f_hi(v[u].w);
    }
  }
  for (; p < c; ++p) {
    uint4 v = Y16[(size_t)csr[start + p] * 8 + li];
    a0 += bf2f_lo(v.x); a1 += bf2f_hi(v.x);
    a2 += bf2f_lo(v.y); a3 += bf2f_hi(v.y);
    a4 += bf2f_lo(v.z); a5 += bf2f_hi(v.z);
    a6 += bf2f_lo(v.w); a7 += bf2f_hi(v.w);
  }
  const float di = deg_inv[node];
  uint4 sv = reinterpret_cast<const uint4*>(Rb)[(size_t)node * 8 + li];
  float s[8] = {bf2f_lo(sv.x), bf2f_hi(sv.x), bf2f_lo(sv.y), bf2f_hi(sv.y),
                bf2f_lo(sv.z), bf2f_hi(sv.z), bf2f_lo(sv.w), bf2f_hi(sv.w)};
  float a[8] = {a0, a1, a2, a3, a4, a5, a6, a7};
#pragma unroll
  for (int j = 0; j < 8; ++j) {
    int f = li * 8 + j;
    if (f < C) out[(size_t)node * C + f] = fmaf(a[j], di, s[j] + bias[f]);
  }
}

// ---------------- host launch ----------------

extern "C" void kernel_launch(void* const* d_in, const int* in_sizes, int n_in,
                              void* d_out, int out_size, void* d_ws, size_t ws_size,
                              hipStream_t stream) {
  const float* x   = (const float*)d_in[0];
  const int*   ei  = (const int*)d_in[1];
  const float* Wl0 = (const float*)d_in[2];
  const float* Wr0 = (const float*)d_in[4];
  const float* g0  = (const float*)d_in[5];
  const float* b0  = (const float*)d_in[6];
  const float* Wl1 = (const float*)d_in[7];
  const float* Wr1 = (const float*)d_in[9];
  const float* g1  = (const float*)d_in[10];
  const float* b1  = (const float*)d_in[11];
  const float* Wl2 = (const float*)d_in[12];
  const float* bl2 = (const float*)d_in[13];
  const float* Wr2 = (const float*)d_in[14];

  const int N = in_sizes[0] / 128;
  const int E = in_sizes[1] / 2;
  const int C = in_sizes[13];  // 47

  const int* edst = ei;
  const int* esrc = ei + E;

  char* w = (char*)d_ws;
  auto al = [](size_t v) { return (v + 255) & ~(size_t)255; };
  size_t off = 0;
  int*    bcur    = (int*)(w + off);    off = al(off + NBUCKETS * 4);
  float*  stats   = (float*)(w + off);  off = al(off + 512 * 4);   // stats0[256] + stats1[256]
  int*    rp      = (int*)(w + off);    off = al(off + (size_t)N * 4);
  int*    deg     = (int*)(w + off);    off = al(off + (size_t)N * 4);
  float*  deg_inv = (float*)(w + off);  off = al(off + (size_t)N * 4);
  int*    csr     = (int*)(w + off);    off = al(off + (size_t)NBUCKETS * SLOT * 4);
  uint*   ebuf    = (uint*)(w + off);   off = al(off + (size_t)NBUCKETS * SLOT * 4);
  ushort* Xb      = (ushort*)(w + off); off = al(off + (size_t)N * 128 * 2);
  ushort* hA      = (ushort*)(w + off); off = al(off + (size_t)N * 128 * 2);
  ushort* hB      = (ushort*)(w + off); off = al(off + (size_t)N * 128 * 2);
  ushort* W0l     = (ushort*)(w + off); off = al(off + 16384 * 2);
  ushort* W0r     = (ushort*)(w + off); off = al(off + 16384 * 2);
  ushort* W1l     = (ushort*)(w + off); off = al(off + 16384 * 2);
  ushort* W1r     = (ushort*)(w + off); off = al(off + 16384 * 2);
  ushort* Wc      = (ushort*)(w + off); off = al(off + 16384 * 2);
  const int nblkG = (N + 63) / 64;
  float*  partial = (float*)(w + off);  off = al(off + (size_t)nblkG * 256 * 4);

  float* stats0 = stats;
  float* stats1 = stats + 256;
  ushort* Yb = hB;                    // layer-2 output reuses hB
  ushort* Rb = hB + (size_t)N * 64;

  const int binGrid = (E + 8191) / 8192;
  const int castGrid = 384;
  const int nbBuck = (N + 1023) / 1024;
  const int agg47Grid = (N + 31) / 32;
  const float invM = 1.0f / (float)N;

  hipMemsetAsync(bcur, 0, NBUCKETS * 4, stream);

  // mega-prep: binscatter + weight casts + x cast + stats zero
  k_prep<<<binGrid + 128 + castGrid + 1, 256, 0, stream>>>(
      edst, esrc, E, bcur, ebuf, x, Xb, N * 32,
      Wl0, Wr0, Wl1, Wr1, Wl2, Wr2, W0l, W0r, W1l, W1r, Wc, stats, C, binGrid, castGrid);

  k_bucket_build<<<nbBuck, 512, 0, stream>>>(ebuf, bcur, rp, deg, deg_inv, csr, N);

  // Layer 0: raw inputs -> hB = Z0; partials -> stats0
  k_fused<<<nblkG, 512, 0, stream>>>(Xb, Xb, W0l, W0r, rp, deg, deg_inv, csr, partial, hB, N);
  k_bn_reduce<<<64, 256, 0, stream>>>(partial, nblkG, stats0);

  // BN+ReLU hB in place (launders the gather source for layer 1)
  k_bn_relu<<<2048, 256, 0, stream>>>((uint2*)hB, N * 32, stats0, g0, b0, invM);

  // Layer 1: clean hB -> hA = Z1; partials -> stats1
  k_fused<<<nblkG, 512, 0, stream>>>(hB, hB, W1l, W1r, rp, deg, deg_inv, csr, partial, hA, N);
  k_bn_reduce<<<64, 256, 0, stream>>>(partial, nblkG, stats1);

  // Layer 2: transform relu(bn(Z1)) @ Wc^T (BN on linear read; split Yb/Rb), then aggregate
  k_gemm1<<<nblkG, 512, 0, stream>>>(hA, Wc, stats1, g1, b1, invM, Yb, Rb, N);
  k_agg47<<<agg47Grid, 256, 0, stream>>>(Yb, Rb, bl2, rp, deg, deg_inv, csr, (float*)d_out, N, C);
}